// Round 3
// baseline (190.572 us; speedup 1.0000x reference)
//
#include <hip/hip_runtime.h>
#include <stdint.h>

#define BATCH 32
#define IMG 512
#define CH 3
#define GOUT 64
#define ROWB (IMG*CH)   // 1536 floats per image row
#define GP   ((size_t)BATCH*CH*GOUT*IMG)   // one K-split partial of planar g

typedef __attribute__((ext_vector_type(8))) short  short8;   // 8 bf16 = 4 VGPRs
typedef __attribute__((ext_vector_type(4))) float  floatx4;  // MFMA 16x16 acc
typedef __attribute__((ext_vector_type(4))) float  floatv4;  // indexable float4

__device__ __forceinline__ unsigned short f2bf(float x) {
    unsigned u = __builtin_bit_cast(unsigned, x);
    u += 0x7FFFu + ((u >> 16) & 1u);
    return (unsigned short)(u >> 16);
}

// async global->LDS 16B copy. LDS dest must be wave-uniform base + lane*16
// (caller guarantees via layout). Proven in round-0 kernel.
typedef __attribute__((address_space(3))) unsigned int  lds_u32;
typedef __attribute__((address_space(1))) const unsigned int g_u32;
__device__ __forceinline__ void async16(const void* g, void* l) {
    __builtin_amdgcn_global_load_lds((g_u32*)(uintptr_t)g,
                                     (lds_u32*)(uintptr_t)l, 16, 0, 0);
}

// ---------------------------------------------------------------------------
// Kernel 1: Gaussian filterbank masks, TRANSPOSED bf16: AyT[b][H][h],
// AxT[b][W][w] (k-contiguous). One wave per (b, axis, r). (unchanged, verified)
// ---------------------------------------------------------------------------
__global__ __launch_bounds__(64) void mask_kernel(const float* __restrict__ tp,
                                                  unsigned short* __restrict__ AyT,
                                                  unsigned short* __restrict__ AxT) {
    int blk  = blockIdx.x;
    int r    = blk & 63;
    int axis = (blk >> 6) & 1;
    int b    = blk >> 7;

    const float* p = tp + b*6 + (axis ? 3 : 0);
    float u = p[0], s = p[1], d = p[2];
    float centre = u + (float)r * d;
    float inv_s  = 1.0f / s;

    int lane = threadIdx.x;
    float e[8];
    float sum = 0.0f;
    #pragma unroll
    for (int i = 0; i < 8; ++i) {
        float z = ((float)(i*64 + lane) - centre) * inv_s;
        e[i] = __expf(-0.5f * z * z);
        sum += e[i];
    }
    #pragma unroll
    for (int m = 1; m < 64; m <<= 1)
        sum += __shfl_xor(sum, m, 64);
    float inv_sum = 1.0f / (sum + 1e-8f);

    unsigned short* dst = (axis ? AxT : AyT) + ((size_t)b*GOUT + r) * IMG;
    #pragma unroll
    for (int i = 0; i < 8; ++i)
        dst[i*64 + lane] = f2bf(e[i] * inv_sum);
}

// ---------------------------------------------------------------------------
// Kernel 2: gP[part][b][c][H][w] = sum_{h in part} Ay[b,h,H]*img[b,h,w,c]
// Round-8: r0-proven skeleton (async global_load_lds staging, fp32 tile,
// 4-way-conflict column reads) + T3 minimum 2-phase double-buffer:
//   prologue STAGE(0); barrier;
//   loop t: STAGE(t+1 -> buf^1) issued FIRST, then compute(buf), then ONE
//   __syncthreads() per chunk (its vmcnt(0) drain lands after ~600cy of
//   compute, hiding the async latency instead of exposing it).
// Ay fragments read directly from L2-resident AyT (16 rows x 64B contiguous
// per instr - r1/r2-verified). LDS = 32 KB dbuf -> 4 blocks/CU, 16 waves/CU.
// ---------------------------------------------------------------------------
__global__ __launch_bounds__(256, 4) void stage1_kernel(const float* __restrict__ img,
                                                        const unsigned short* __restrict__ AyT,
                                                        float* __restrict__ gP) {
    __shared__ float Bs[2][64][64];   // [buf][h][wc], UNPADDED (async dest)

    int part = blockIdx.x & 1;
    int bt   = blockIdx.x >> 1;
    int tile = bt % 24;
    int b    = bt / 24;
    int wc0  = tile * 64;
    int tid  = threadIdx.x;
    int wave = tid >> 6;
    int lane = tid & 63;
    int n16  = lane & 15;
    int q    = lane >> 4;

    floatx4 acc[4];
    #pragma unroll
    for (int mt = 0; mt < 4; ++mt) acc[mt] = (floatx4){0.f, 0.f, 0.f, 0.f};

    const float*          imb = img + (size_t)b * IMG * ROWB + wc0;
    const unsigned short* ayb = AyT + (size_t)b * GOUT * IMG;

    int rb = wave*4 + q;   // async row base: wave-contiguous lane*16 dest
    int cg = n16;          // float4 within row
    int h0 = part * 256;

    // STAGE(t, buf): 4 async16 per lane, each wave writes 4 rows x 256B.
    #define STAGE(t, buf) do { \
        _Pragma("unroll") \
        for (int i = 0; i < 4; ++i) { \
            int r_ = rb + i*16; \
            async16(imb + (size_t)(h0 + (t)*64 + r_) * ROWB + cg*4, &Bs[buf][r_][cg*4]); \
        } \
    } while (0)

    STAGE(0, 0);
    __syncthreads();   // drains vmcnt(0): buf0 ready

    int cur = 0;
    for (int t = 0; t < 4; ++t) {
        if (t < 3) STAGE(t+1, cur ^ 1);   // issue next tile BEFORE compute

        int hb = h0 + t*64;
        #pragma unroll
        for (int s = 0; s < 2; ++s) {
            short8 bf;
            #pragma unroll
            for (int j = 0; j < 8; ++j)
                bf[j] = (short)f2bf(Bs[cur][s*32 + q*8 + j][wave*16 + n16]);
            int hk = hb + s*32 + q*8;
            #pragma unroll
            for (int mt = 0; mt < 4; ++mt) {
                short8 af = *(const short8*)(ayb + (size_t)(mt*16 + n16) * IMG + hk);
                acc[mt] = __builtin_amdgcn_mfma_f32_16x16x32_bf16(af, bf, acc[mt], 0, 0, 0);
            }
        }
        __syncthreads();   // one barrier/chunk: drains next-buf asyncs too
        cur ^= 1;
    }
    #undef STAGE

    // Epilogue: D col = lane&15 -> wc, row = q*4+reg -> H (verified r4/r5).
    int wc = wc0 + wave*16 + n16;
    int c = wc % 3, w = wc / 3;
    float* gb = gP + (size_t)part * GP + ((size_t)(b*CH + c) * GOUT) * IMG + w;
    #pragma unroll
    for (int mt = 0; mt < 4; ++mt)
        #pragma unroll
        for (int reg = 0; reg < 4; ++reg)
            gb[(size_t)(mt*16 + q*4 + reg) * IMG] = acc[mt][reg];
}

// ---------------------------------------------------------------------------
// Kernel 3: out[b,H,W,c] += sum_{w in part} (g0+g1)[b,c,H,w] * Ax[b,w,W]
// Round-8: r2's verified indexing (K-split 2, 768 blocks, 2-way atomics) but
// with EXPLICIT register prefetch: 2 phases x 4 K-chunks; all 20 independent
// 16B loads of a phase issued before any convert/MFMA (static-indexed arrays,
// 128-VGPR budget) -> ~20 loads in flight per wave instead of ~2.
// ---------------------------------------------------------------------------
__global__ __launch_bounds__(256, 4) void stage2_kernel(const float* __restrict__ gP,
                                                        const unsigned short* __restrict__ AxT,
                                                        float* __restrict__ out) {
    int blk  = blockIdx.x;
    int part = blk & 1;
    int hq   = (blk >> 1) & 3;    // H-quadrant (16 rows)
    int bc   = blk >> 3;
    int c    = bc % 3;
    int b    = bc / 3;
    int tid  = threadIdx.x;
    int wq   = tid >> 6;          // owns W-tile wq*16..+15
    int lane = tid & 63;
    int n16  = lane & 15;
    int q    = lane >> 4;

    floatx4 acc = (floatx4){0.f, 0.f, 0.f, 0.f};

    const float*          ga  = gP  + ((size_t)(b*CH + c) * GOUT + hq*16 + n16) * IMG;
    const unsigned short* axb = AxT + ((size_t)b*GOUT + wq*16 + n16) * IMG;

    #pragma unroll
    for (int ph = 0; ph < 2; ++ph) {
        floatv4 A0[4], A1[4], B0[4], B1[4];
        short8  BF[4];
        #pragma unroll
        for (int cc = 0; cc < 4; ++cc) {
            int w0 = part*256 + ph*128 + cc*32 + q*8;
            A0[cc] = *(const floatv4*)(ga + w0);
            A1[cc] = *(const floatv4*)(ga + w0 + 4);
            B0[cc] = *(const floatv4*)(ga + GP + w0);
            B1[cc] = *(const floatv4*)(ga + GP + w0 + 4);
            BF[cc] = *(const short8*)(axb + w0);
        }
        #pragma unroll
        for (int cc = 0; cc < 4; ++cc) {
            short8 af;
            af[0] = (short)f2bf(A0[cc][0] + B0[cc][0]);
            af[1] = (short)f2bf(A0[cc][1] + B0[cc][1]);
            af[2] = (short)f2bf(A0[cc][2] + B0[cc][2]);
            af[3] = (short)f2bf(A0[cc][3] + B0[cc][3]);
            af[4] = (short)f2bf(A1[cc][0] + B1[cc][0]);
            af[5] = (short)f2bf(A1[cc][1] + B1[cc][1]);
            af[6] = (short)f2bf(A1[cc][2] + B1[cc][2]);
            af[7] = (short)f2bf(A1[cc][3] + B1[cc][3]);
            acc = __builtin_amdgcn_mfma_f32_16x16x32_bf16(af, BF[cc], acc, 0, 0, 0);
        }
    }

    float* ob = out + (((size_t)b*GOUT + hq*16) * GOUT + wq*16 + n16) * CH + c;
    #pragma unroll
    for (int reg = 0; reg < 4; ++reg)
        atomicAdd(ob + (size_t)(q*4 + reg) * GOUT * CH, acc[reg]);
}

// ---------------------------------------------------------------------------
// Workspace: AyT 2 MB | AxT 2 MB | gP 2 x 12.6 MB  (~29 MB).
// ---------------------------------------------------------------------------
extern "C" void kernel_launch(void* const* d_in, const int* in_sizes, int n_in,
                              void* d_out, int out_size, void* d_ws, size_t ws_size,
                              hipStream_t stream) {
    const float* img = (const float*)d_in[0];
    const float* tp  = (const float*)d_in[1];
    float* out = (float*)d_out;

    unsigned short* AyT = (unsigned short*)d_ws;
    unsigned short* AxT = AyT + (size_t)BATCH * GOUT * IMG;
    float*          gPp = (float*)(AxT + (size_t)BATCH * GOUT * IMG);

    hipMemsetAsync(d_out, 0, (size_t)out_size * sizeof(float), stream);
    mask_kernel  <<<BATCH * 2 * GOUT,    64, 0, stream>>>(tp, AyT, AxT);
    stage1_kernel<<<BATCH * 24 * 2,     256, 0, stream>>>(img, AyT, gPp);
    stage2_kernel<<<BATCH * CH * 4 * 2, 256, 0, stream>>>(gPp, AxT, out);
}